// Round 4
// baseline (11.310 us; speedup 1.0000x reference)
//
#include <hip/hip_runtime.h>

// loss = mean_i( log_qz_cond_x[i] - log_pz[i] )
//      = (1/B) * sum_{i,d} [ -log(scale) + 0.5*z^2 - 0.5*((z-loc)/scale)^2 ]
// (MI_W=TC_W=KL_W=1 telescopes the decomposition; log_qz and log_qz_prod
//  cancel exactly, so the B*B*D pairwise matrix is never needed.)
//
// TWO-KERNEL design, deliberately: the single-kernel last-block-done
// counter protocol flaked in R3 (absmax 1.5 == ~2 stale partials in the
// final gather => cross-XCD visibility race). Stream ordering between two
// kernels gives coherence by construction (end-of-kernel flush), costs
// ~0.6 us of node overhead, and is bitwise-deterministic every replay.

#define BATCH 2048
#define NELEM (BATCH * 64)          // 131072
#define NVEC (NELEM / 4)            // 32768 float4 per input
#define BLOCKS 64
#define THREADS 512                 // BLOCKS*THREADS == NVEC exactly

__global__ __launch_bounds__(THREADS) void kld_partial_kernel(
    const float* __restrict__ z, const float* __restrict__ loc,
    const float* __restrict__ scale, double* __restrict__ partials) {
    int idx = blockIdx.x * THREADS + threadIdx.x;   // 0 .. NVEC-1
    float4 zv = reinterpret_cast<const float4*>(z)[idx];
    float4 lv = reinterpret_cast<const float4*>(loc)[idx];
    float4 sv = reinterpret_cast<const float4*>(scale)[idx];

    float tx = (zv.x - lv.x) / sv.x;
    float ty = (zv.y - lv.y) / sv.y;
    float tz = (zv.z - lv.z) / sv.z;
    float tw = (zv.w - lv.w) / sv.w;
    float q  = 0.5f * (zv.x * zv.x + zv.y * zv.y + zv.z * zv.z + zv.w * zv.w
                       - tx * tx - ty * ty - tz * tz - tw * tw);
    // sum of log(s) over 4 elems = log of the product (range [0.0625, 5.07))
    float acc = q - logf(sv.x * sv.y * sv.z * sv.w);

    double d = (double)acc;
    #pragma unroll
    for (int off = 32; off > 0; off >>= 1)
        d += __shfl_down(d, off, 64);

    __shared__ double sm[THREADS / 64];
    int lane = threadIdx.x & 63;
    int wid  = threadIdx.x >> 6;
    if (lane == 0) sm[wid] = d;
    __syncthreads();
    if (threadIdx.x == 0) {
        double s = 0.0;
        #pragma unroll
        for (int w = 0; w < THREADS / 64; ++w) s += sm[w];
        partials[blockIdx.x] = s;
    }
}

__global__ __launch_bounds__(64) void kld_final_kernel(
    const double* __restrict__ partials, float* __restrict__ out) {
    // one wave: lane i holds partials[i], fixed-order shuffle reduce
    double v = partials[threadIdx.x];
    #pragma unroll
    for (int off = 32; off > 0; off >>= 1)
        v += __shfl_down(v, off, 64);
    if (threadIdx.x == 0)
        out[0] = (float)(v / (double)BATCH);
}

extern "C" void kernel_launch(void* const* d_in, const int* in_sizes, int n_in,
                              void* d_out, int out_size, void* d_ws, size_t ws_size,
                              hipStream_t stream) {
    const float* z     = (const float*)d_in[0];
    const float* loc   = (const float*)d_in[1];
    const float* scale = (const float*)d_in[2];
    float* out = (float*)d_out;
    double* partials   = (double*)d_ws;

    kld_partial_kernel<<<BLOCKS, THREADS, 0, stream>>>(z, loc, scale, partials);
    kld_final_kernel<<<1, 64, 0, stream>>>(partials, out);
}